// Round 3
// baseline (860.803 us; speedup 1.0000x reference)
//
#include <hip/hip_runtime.h>
#include <hip/hip_bf16.h>
#include <stdint.h>
#include <stddef.h>

// Problem constants (GRUTridentDecoder: B=32,H=256,V=512,A=3,NANN=8,DEPTH=7)
#define NB 32
#define NH 256
#define NMID 512      // 2*H
#define NV 512
#define NA 3
#define NDEPTH 7
#define NNODES 3280   // (3^8-1)/2
#define NG 2304       // A*3H
#define MROWS (NNODES * NB)  // 104960
#define HM 64         // fused-head rows per block

typedef __attribute__((ext_vector_type(8))) short bf16x8;
typedef __attribute__((ext_vector_type(4))) float f32x4;

__device__ __forceinline__ unsigned short f2bf(float x) {
    union { float f; unsigned u; } v; v.f = x;
    unsigned r = v.u + 0x7fffu + ((v.u >> 16) & 1u);
    return (unsigned short)(r >> 16);
}
__device__ __forceinline__ float sigm(float x) { return 1.0f / (1.0f + __expf(-x)); }
__device__ __forceinline__ float tanh_(float x) {
    x = fminf(fmaxf(x, -15.0f), 15.0f);
    float e = __expf(2.0f * x);
    return (e - 1.0f) / (e + 1.0f);
}

// ---- prep: cast weights fp32 -> bf16 (whh 2304x256, w1 512x256, w2 512x512)
__global__ void cast_weights(const float* __restrict__ whh, const float* __restrict__ w1,
                             const float* __restrict__ w2,
                             unsigned short* __restrict__ whh_b,
                             unsigned short* __restrict__ w1_b,
                             unsigned short* __restrict__ w2_b) {
    const int n_whh = NG * NH;          // 589824
    const int n_w1  = NMID * NH;        // 131072
    const int n_w2  = NV * NMID;        // 262144
    const int total = n_whh + n_w1 + n_w2;
    for (int i = blockIdx.x * blockDim.x + threadIdx.x; i < total;
         i += gridDim.x * blockDim.x) {
        if (i < n_whh) whh_b[i] = f2bf(whh[i]);
        else if (i < n_whh + n_w1) w1_b[i - n_whh] = f2bf(w1[i - n_whh]);
        else w2_b[i - n_whh - n_w1] = f2bf(w2[i - n_whh - n_w1]);
    }
}

// ---- prep: gx[b][col] = dot(ann_table[ann_ids[b]], w_ih[col]) + b_ih[col]
__global__ void gx_kernel(const float* __restrict__ ann_table, const int* __restrict__ ann_ids,
                          const float* __restrict__ w_ih, const float* __restrict__ b_ih,
                          float* __restrict__ gx) {
    int gw = blockIdx.x * (blockDim.x >> 6) + (threadIdx.x >> 6);
    int lane = threadIdx.x & 63;
    if (gw >= NB * NG) return;
    int b = gw / NG;
    int col = gw - b * NG;
    const float* xr = ann_table + (size_t)ann_ids[b] * NH;
    const float* wr = w_ih + (size_t)col * NH;
    float4 xv = *(const float4*)(xr + lane * 4);
    float4 wv = *(const float4*)(wr + lane * 4);
    float s = xv.x * wv.x + xv.y * wv.y + xv.z * wv.z + xv.w * wv.w;
    #pragma unroll
    for (int off = 32; off; off >>= 1) s += __shfl_down(s, off);
    if (lane == 0) gx[(size_t)b * NG + col] = s + b_ih[col];
}

// ---- prep: root hidden into node 0 (layout hid[(node*32+b)*256+h])
__global__ void init_root(const float* __restrict__ root, float* __restrict__ hid_f,
                          unsigned short* __restrict__ hid_b) {
    int i = blockIdx.x * blockDim.x + threadIdx.x;
    if (i < NB * NH) { float v = root[i]; hid_f[i] = v; hid_b[i] = f2bf(v); }
}

// ---- prep: preorder position of each level-order node
__global__ void posmap_kernel(int* __restrict__ posmap) {
    int n = blockIdx.x * blockDim.x + threadIdx.x;
    if (n >= NNODES) return;
    int start = 0, cnt = 1, l = 0;
    while (n >= start + cnt) { start += cnt; cnt *= 3; l++; }
    int p = n - start;
    int pw = 1;
    for (int j = 0; j < l - 1; j++) pw *= 3;   // 3^(l-1)
    int pos = 0;
    for (int k = 1; k <= l; k++) {
        int d = (p / pw) % 3;
        int e = NDEPTH - k + 1;                // subtree height exponent
        int p3 = 1; for (int j = 0; j < e; j++) p3 *= 3;
        pos += 1 + d * ((p3 - 1) / 2);
        pw /= 3;
    }
    posmap[n] = pos;
}

// ---- GRU level (v2): one block = one parent node (M=32 rows). 8 waves cover all
// 3 arities x 768 gate-cols: wave w owns flat (a,h') cols [w*96, w*96+96), all 3
// gates. A-tile (32x256 bf16 = 16KB) reg-staged into XOR-swizzled LDS, shared by
// all waves. 36 MFMA per K-step per wave; B-frags direct from L2-resident whh.
__global__ __launch_bounds__(512, 2)
void gru_level(const unsigned short* __restrict__ hid_b_in,
               unsigned short* __restrict__ hid_b_out,
               const float* __restrict__ hid_f_in, float* __restrict__ hid_f_out,
               const unsigned short* __restrict__ whh_b,
               const float* __restrict__ b_hh, const float* __restrict__ gx,
               int start, int child_start) {
    __shared__ char a_s[32 * 512];   // 32 rows x 256 bf16, swizzled

    int tid = threadIdx.x;
    int lane = tid & 63;
    int wv = tid >> 6;
    int lr = lane & 15;
    int kg = (lane >> 4) * 8;        // k sub-offset (elements)
    int rbase = (lane >> 4) * 4;
    int nrel = blockIdx.x;           // parent node index within level
    size_t prow0 = (size_t)(start + nrel) * NB;  // first parent row

    // ---- stage A-tile (32x256) into swizzled LDS
    #pragma unroll
    for (int c = tid; c < 1024; c += 512) {
        int row = c >> 5;              // 32 chunks of 8 elems per row
        int coloff = (c & 31) * 8;
        bf16x8 v = *(const bf16x8*)(hid_b_in + (prow0 + row) * NH + coloff);
        int byteoff = (row * 512 + coloff * 2) ^ ((row & 7) << 4);
        *(bf16x8*)(a_s + byteoff) = v;
    }
    __syncthreads();

    // ---- per-wave column geometry: flat G = a*256 + h'
    const unsigned short* bptr[6];
    int abase[6], hbase[6];
    #pragma unroll
    for (int ni = 0; ni < 6; ++ni) {
        int Gb = wv * 96 + ni * 16;
        int a = Gb >> 8;
        abase[ni] = a;
        hbase[ni] = Gb & 255;
        // whh row = a*768 + t*256 + h' = a*512 + Gb (+ t*256); +lr per lane
        bptr[ni] = whh_b + (size_t)(a * 512 + Gb + lr) * NH + kg;
    }

    f32x4 acc[3][2][6] = {};
    for (int k0 = 0; k0 < NH; k0 += 32) {
        bf16x8 af[2];
        #pragma unroll
        for (int mi = 0; mi < 2; ++mi) {
            int row = mi * 16 + lr;
            int byteoff = (row * 512 + (k0 + kg) * 2) ^ ((row & 7) << 4);
            af[mi] = *(const bf16x8*)(a_s + byteoff);
        }
        #pragma unroll
        for (int ni = 0; ni < 6; ++ni) {
            #pragma unroll
            for (int t = 0; t < 3; ++t) {
                bf16x8 bfr = *(const bf16x8*)(bptr[ni] + t * 256 * NH + k0);
                #pragma unroll
                for (int mi = 0; mi < 2; ++mi)
                    acc[t][mi][ni] = __builtin_amdgcn_mfma_f32_16x16x32_bf16(af[mi], bfr, acc[t][mi][ni], 0, 0, 0);
            }
        }
    }

    // ---- epilogue: gates + child writes
    #pragma unroll
    for (int ni = 0; ni < 6; ++ni) {
        int a = abase[ni];
        int colh = hbase[ni] + lr;                 // h' column
        float bh_r = b_hh[a * 768 + colh];
        float bh_z = b_hh[a * 768 + 256 + colh];
        float bh_n = b_hh[a * 768 + 512 + colh];
        #pragma unroll
        for (int mi = 0; mi < 2; ++mi) {
            #pragma unroll
            for (int j = 0; j < 4; ++j) {
                int b = mi * 16 + rbase + j;       // batch row (M=32 = one node)
                const float* gxb = gx + (size_t)b * NG + a * 768;
                float rpre = acc[0][mi][ni][j] + bh_r + gxb[colh];
                float zpre = acc[1][mi][ni][j] + bh_z + gxb[256 + colh];
                float hn   = acc[2][mi][ni][j] + bh_n;
                float xn   = gxb[512 + colh];
                float r = sigm(rpre), z = sigm(zpre);
                float nn = tanh_(xn + r * hn);
                float hpv = hid_f_in[(prow0 + b) * NH + colh];
                float hnew = (1.0f - z) * nn + z * hpv;
                size_t crow = ((size_t)(child_start + nrel * 3 + a)) * NB + b;
                hid_f_out[crow * NH + colh] = hnew;
                hid_b_out[crow * NH + colh] = f2bf(hnew);
            }
        }
    }
}

// ---- fused head: per block of 64 rows, mid = sigmoid(hid@w1^T+b1) in LDS (bf16,
// XOR-swizzled), then out = mid@w2^T + b2 with permuted store.
__global__ __launch_bounds__(256, 2)
void head_fused(const unsigned short* __restrict__ hid_b,
                const unsigned short* __restrict__ w1_b, const float* __restrict__ b1,
                const unsigned short* __restrict__ w2_b, const float* __restrict__ b2,
                const int* __restrict__ posmap, float* __restrict__ out) {
    __shared__ unsigned short mid_s[HM * NMID];  // 64 KB

    int lane = threadIdx.x & 63;
    int wv = threadIdx.x >> 6;
    int mbase = blockIdx.x * HM;
    int lr = lane & 15;
    int kg = (lane >> 4) * 8;
    int rbase = (lane >> 4) * 4;
    int n0w = wv * 128;

    f32x4 acc[4][8];

    // ---- phase 1: mid tile
    #pragma unroll
    for (int mi = 0; mi < 4; ++mi)
        #pragma unroll
        for (int ni = 0; ni < 8; ++ni) acc[mi][ni] = (f32x4){0.f, 0.f, 0.f, 0.f};

    {
        const unsigned short* abase = hid_b + ((size_t)(mbase + lr)) * NH + kg;
        const unsigned short* bbase = w1_b + ((size_t)(n0w + lr)) * NH + kg;
        for (int k0 = 0; k0 < NH; k0 += 32) {
            bf16x8 af[4], bfr[8];
            #pragma unroll
            for (int mi = 0; mi < 4; ++mi) af[mi] = *(const bf16x8*)(abase + mi * 16 * NH + k0);
            #pragma unroll
            for (int ni = 0; ni < 8; ++ni) bfr[ni] = *(const bf16x8*)(bbase + ni * 16 * NH + k0);
            #pragma unroll
            for (int mi = 0; mi < 4; ++mi)
                #pragma unroll
                for (int ni = 0; ni < 8; ++ni)
                    acc[mi][ni] = __builtin_amdgcn_mfma_f32_16x16x32_bf16(af[mi], bfr[ni], acc[mi][ni], 0, 0, 0);
        }
    }
    // epilogue 1: sigmoid -> bf16 -> LDS (swizzled: byte ^= (row&7)<<4)
    #pragma unroll
    for (int mi = 0; mi < 4; ++mi)
        #pragma unroll
        for (int ni = 0; ni < 8; ++ni) {
            int col = n0w + ni * 16 + lr;
            float bv = b1[col];
            #pragma unroll
            for (int j = 0; j < 4; ++j) {
                int row = mi * 16 + rbase + j;
                float v = sigm(acc[mi][ni][j] + bv);
                int byteoff = (row * NMID + col) * 2;
                byteoff ^= (row & 7) << 4;
                *(unsigned short*)((char*)mid_s + byteoff) = f2bf(v);
            }
        }
    __syncthreads();

    // ---- phase 2: out tile
    #pragma unroll
    for (int mi = 0; mi < 4; ++mi)
        #pragma unroll
        for (int ni = 0; ni < 8; ++ni) acc[mi][ni] = (f32x4){0.f, 0.f, 0.f, 0.f};

    {
        const unsigned short* bbase = w2_b + ((size_t)(n0w + lr)) * NMID + kg;
        for (int k0 = 0; k0 < NMID; k0 += 32) {
            bf16x8 af[4], bfr[8];
            #pragma unroll
            for (int mi = 0; mi < 4; ++mi) {
                int row = mi * 16 + lr;
                int byteoff = (row * NMID + k0 + kg) * 2;
                byteoff ^= (row & 7) << 4;
                af[mi] = *(const bf16x8*)((char*)mid_s + byteoff);
            }
            #pragma unroll
            for (int ni = 0; ni < 8; ++ni) bfr[ni] = *(const bf16x8*)(bbase + ni * 16 * NMID + k0);
            #pragma unroll
            for (int mi = 0; mi < 4; ++mi)
                #pragma unroll
                for (int ni = 0; ni < 8; ++ni)
                    acc[mi][ni] = __builtin_amdgcn_mfma_f32_16x16x32_bf16(af[mi], bfr[ni], acc[mi][ni], 0, 0, 0);
        }
    }
    // epilogue 2: bias + permuted store
    #pragma unroll
    for (int mi = 0; mi < 4; ++mi)
        #pragma unroll
        for (int ni = 0; ni < 8; ++ni) {
            int col = n0w + ni * 16 + lr;
            float bv = b2[col];
            #pragma unroll
            for (int j = 0; j < 4; ++j) {
                int row = mbase + mi * 16 + rbase + j;
                int b = row & 31;
                int node = row >> 5;
                int pos = posmap[node];
                out[((size_t)pos * NB + b) * NV + col] = acc[mi][ni][j] + bv;
            }
        }
}

extern "C" void kernel_launch(void* const* d_in, const int* in_sizes, int n_in,
                              void* d_out, int out_size, void* d_ws, size_t ws_size,
                              hipStream_t stream) {
    const float* root      = (const float*)d_in[0];
    const float* ann_table = (const float*)d_in[1];
    const float* w1        = (const float*)d_in[2];
    const float* b1        = (const float*)d_in[3];
    const float* w2        = (const float*)d_in[4];
    const float* b2        = (const float*)d_in[5];
    const float* w_ih      = (const float*)d_in[6];
    const float* w_hh      = (const float*)d_in[7];
    const float* b_ih      = (const float*)d_in[8];
    const float* b_hh      = (const float*)d_in[9];
    const int*   ann_ids   = (const int*)d_in[10];

    uint8_t* ws = (uint8_t*)d_ws;
    unsigned short* whh_b = (unsigned short*)ws; ws += (size_t)NG * NH * 2;      // 1.18 MB
    unsigned short* w1_b  = (unsigned short*)ws; ws += (size_t)NMID * NH * 2;    // 0.26 MB
    unsigned short* w2_b  = (unsigned short*)ws; ws += (size_t)NV * NMID * 2;    // 0.52 MB
    float* gx             = (float*)ws;          ws += (size_t)NB * NG * 4;      // 0.29 MB
    int* posmap           = (int*)ws;            ws += (size_t)NNODES * 4;       // 13 KB
    unsigned short* hid_b = (unsigned short*)ws; ws += (size_t)NNODES * NB * NH * 2; // 53.7 MB
    float* hid_f          = (float*)ws;          // 107.5 MB

    cast_weights<<<512, 256, 0, stream>>>(w_hh, w1, w2, whh_b, w1_b, w2_b);
    gx_kernel<<<(NB * NG) / 4, 256, 0, stream>>>(ann_table, ann_ids, w_ih, b_ih, gx);
    init_root<<<(NB * NH + 255) / 256, 256, 0, stream>>>(root, hid_f, hid_b);
    posmap_kernel<<<(NNODES + 255) / 256, 256, 0, stream>>>(posmap);

    int start = 0, cnt = 1;
    for (int l = 0; l < NDEPTH; ++l) {
        int child_start = start + cnt;
        gru_level<<<cnt, 512, 0, stream>>>(hid_b, hid_b, hid_f, hid_f,
                                           whh_b, b_hh, gx, start, child_start);
        start = child_start; cnt *= 3;
    }
    head_fused<<<MROWS / HM, 256, 0, stream>>>(hid_b, w1_b, b1, w2_b, b2, posmap, (float*)d_out);
}

// Round 4
// 513.296 us; speedup vs baseline: 1.6770x; 1.6770x over previous
//
#include <hip/hip_runtime.h>
#include <hip/hip_bf16.h>
#include <stdint.h>
#include <stddef.h>

// Problem constants (GRUTridentDecoder: B=32,H=256,V=512,A=3,NANN=8,DEPTH=7)
#define NB 32
#define NH 256
#define NMID 512      // 2*H
#define NV 512
#define NA 3
#define NDEPTH 7
#define NNODES 3280   // (3^8-1)/2
#define NG 2304       // A*3H
#define MROWS (NNODES * NB)  // 104960
#define HM 64         // fused-head rows per block

typedef __attribute__((ext_vector_type(8))) short bf16x8;
typedef __attribute__((ext_vector_type(4))) float f32x4;

__device__ __forceinline__ unsigned short f2bf(float x) {
    union { float f; unsigned u; } v; v.f = x;
    unsigned r = v.u + 0x7fffu + ((v.u >> 16) & 1u);
    return (unsigned short)(r >> 16);
}
__device__ __forceinline__ float bf2f(unsigned short u) {
    union { unsigned u; float f; } v; v.u = ((unsigned)u) << 16;
    return v.f;
}
__device__ __forceinline__ float sigm(float x) { return 1.0f / (1.0f + __expf(-x)); }
__device__ __forceinline__ float tanh_(float x) {
    x = fminf(fmaxf(x, -15.0f), 15.0f);
    float e = __expf(2.0f * x);
    return (e - 1.0f) / (e + 1.0f);
}
__device__ __forceinline__ f32x4 splat4(float s) { f32x4 v = {s, s, s, s}; return v; }

// ---- prep: cast weights fp32 -> bf16
__global__ void cast_weights(const float* __restrict__ whh, const float* __restrict__ w1,
                             const float* __restrict__ w2,
                             unsigned short* __restrict__ whh_b,
                             unsigned short* __restrict__ w1_b,
                             unsigned short* __restrict__ w2_b) {
    const int n_whh = NG * NH;
    const int n_w1  = NMID * NH;
    const int n_w2  = NV * NMID;
    const int total = n_whh + n_w1 + n_w2;
    for (int i = blockIdx.x * blockDim.x + threadIdx.x; i < total;
         i += gridDim.x * blockDim.x) {
        if (i < n_whh) whh_b[i] = f2bf(whh[i]);
        else if (i < n_whh + n_w1) w1_b[i - n_whh] = f2bf(w1[i - n_whh]);
        else w2_b[i - n_whh - n_w1] = f2bf(w2[i - n_whh - n_w1]);
    }
}

// ---- prep: gx_t[col][b] = dot(ann_table[ann_ids[b]], w_ih[col]) + b_ih[col]  (TRANSPOSED)
__global__ void gx_kernel(const float* __restrict__ ann_table, const int* __restrict__ ann_ids,
                          const float* __restrict__ w_ih, const float* __restrict__ b_ih,
                          float* __restrict__ gx_t) {
    int gw = blockIdx.x * (blockDim.x >> 6) + (threadIdx.x >> 6);
    int lane = threadIdx.x & 63;
    if (gw >= NB * NG) return;
    int b = gw / NG;
    int col = gw - b * NG;
    const float* xr = ann_table + (size_t)ann_ids[b] * NH;
    const float* wr = w_ih + (size_t)col * NH;
    float4 xv = *(const float4*)(xr + lane * 4);
    float4 wv = *(const float4*)(wr + lane * 4);
    float s = xv.x * wv.x + xv.y * wv.y + xv.z * wv.z + xv.w * wv.w;
    #pragma unroll
    for (int off = 32; off; off >>= 1) s += __shfl_down(s, off);
    if (lane == 0) gx_t[(size_t)col * NB + b] = s + b_ih[col];
}

// ---- prep: root hidden into node 0 (bf16 only)
__global__ void init_root(const float* __restrict__ root, unsigned short* __restrict__ hid_b) {
    int i = blockIdx.x * blockDim.x + threadIdx.x;
    if (i < NB * NH) hid_b[i] = f2bf(root[i]);
}

// ---- prep: preorder position of each level-order node
__global__ void posmap_kernel(int* __restrict__ posmap) {
    int n = blockIdx.x * blockDim.x + threadIdx.x;
    if (n >= NNODES) return;
    int start = 0, cnt = 1, l = 0;
    while (n >= start + cnt) { start += cnt; cnt *= 3; l++; }
    int p = n - start;
    int pw = 1;
    for (int j = 0; j < l - 1; j++) pw *= 3;
    int pos = 0;
    for (int k = 1; k <= l; k++) {
        int d = (p / pw) % 3;
        int e = NDEPTH - k + 1;
        int p3 = 1; for (int j = 0; j < e; j++) p3 *= 3;
        pos += 1 + d * ((p3 - 1) / 2);
        pw /= 3;
    }
    posmap[n] = pos;
}

// ---- GRU level v3: one parent node per blockIdx.x; columns split across
// blockIdx.y (6/NI splits). Wave wv owns NI*16 flat (a,h') cols, all 3 gates.
// gx folded into acc-init via transposed gx_t; hidden state bf16-only; parent
// h re-read from swizzled LDS A-tile.
template<int NI>
__global__ __launch_bounds__(512, 2)
void gru_level(const unsigned short* __restrict__ hid_b_in,
               unsigned short* __restrict__ hid_b_out,
               const unsigned short* __restrict__ whh_b,
               const float* __restrict__ b_hh, const float* __restrict__ gx_t,
               int start, int child_start) {
    __shared__ char a_s[32 * 512];   // 32 rows x 256 bf16, swizzled

    int tid = threadIdx.x;
    int lane = tid & 63;
    int wv = tid >> 6;
    int lr = lane & 15;
    int kg = (lane >> 4) * 8;
    int rbase = (lane >> 4) * 4;
    int nrel = blockIdx.x;
    size_t prow0 = (size_t)(start + nrel) * NB;

    // stage A-tile (32x256 bf16) into swizzled LDS
    #pragma unroll
    for (int c = tid; c < 1024; c += 512) {
        int row = c >> 5;
        int coloff = (c & 31) * 8;
        bf16x8 v = *(const bf16x8*)(hid_b_in + (prow0 + row) * NH + coloff);
        int byteoff = (row * 512 + coloff * 2) ^ ((row & 7) << 4);
        *(bf16x8*)(a_s + byteoff) = v;
    }
    __syncthreads();

    // per-wave column geometry: flat G = a*256 + h'
    const unsigned short* bptr[NI];
    int abase[NI], gcol[NI];
    #pragma unroll
    for (int ni = 0; ni < NI; ++ni) {
        int Gb = blockIdx.y * (NI * 128) + wv * (NI * 16) + ni * 16;
        int a = Gb >> 8;
        abase[ni] = a;
        gcol[ni] = a * 768 + (Gb & 255) + lr;  // gate-r flat column for this lane
        bptr[ni] = whh_b + (size_t)(a * 512 + Gb + lr) * NH + kg;
    }

    // acc init: fold gx (r,z) + b_hh
    f32x4 acc[3][2][NI];
    #pragma unroll
    for (int ni = 0; ni < NI; ++ni) {
        float bhr = b_hh[gcol[ni]];
        float bhz = b_hh[gcol[ni] + 256];
        float bhn = b_hh[gcol[ni] + 512];
        #pragma unroll
        for (int mi = 0; mi < 2; ++mi) {
            f32x4 gr = *(const f32x4*)(gx_t + (size_t)gcol[ni] * NB + mi * 16 + rbase);
            f32x4 gz = *(const f32x4*)(gx_t + (size_t)(gcol[ni] + 256) * NB + mi * 16 + rbase);
            acc[0][mi][ni] = gr + splat4(bhr);
            acc[1][mi][ni] = gz + splat4(bhz);
            acc[2][mi][ni] = splat4(bhn);
        }
    }

    for (int k0 = 0; k0 < NH; k0 += 32) {
        bf16x8 af[2];
        #pragma unroll
        for (int mi = 0; mi < 2; ++mi) {
            int row = mi * 16 + lr;
            int byteoff = (row * 512 + (k0 + kg) * 2) ^ ((row & 7) << 4);
            af[mi] = *(const bf16x8*)(a_s + byteoff);
        }
        #pragma unroll
        for (int ni = 0; ni < NI; ++ni) {
            #pragma unroll
            for (int t = 0; t < 3; ++t) {
                bf16x8 bfr = *(const bf16x8*)(bptr[ni] + t * 256 * NH + k0);
                #pragma unroll
                for (int mi = 0; mi < 2; ++mi)
                    acc[t][mi][ni] = __builtin_amdgcn_mfma_f32_16x16x32_bf16(af[mi], bfr, acc[t][mi][ni], 0, 0, 0);
            }
        }
    }

    // epilogue: gates + bf16 child writes; parent h from LDS
    #pragma unroll
    for (int ni = 0; ni < NI; ++ni) {
        int a = abase[ni];
        int colh = gcol[ni] - a * 768;             // h' column (with +lr)
        size_t crow = ((size_t)(child_start + nrel * 3 + a)) * NB;
        #pragma unroll
        for (int mi = 0; mi < 2; ++mi) {
            f32x4 xn4 = *(const f32x4*)(gx_t + (size_t)(gcol[ni] + 512) * NB + mi * 16 + rbase);
            #pragma unroll
            for (int j = 0; j < 4; ++j) {
                int b = mi * 16 + rbase + j;
                float r = sigm(acc[0][mi][ni][j]);
                float z = sigm(acc[1][mi][ni][j]);
                float nn = tanh_(xn4[j] + r * acc[2][mi][ni][j]);
                unsigned short hpu = *(const unsigned short*)(a_s + ((b * 512 + colh * 2) ^ ((b & 7) << 4)));
                float hnew = (1.0f - z) * nn + z * bf2f(hpu);
                hid_b_out[(crow + b) * NH + colh] = f2bf(hnew);
            }
        }
    }
}

// ---- fused head: 512 threads, 8 waves; per block 64 rows; wave owns 64 cols.
// mid tile in swizzled LDS; VGPR capped at 128 for 2 blocks/CU.
__global__ __launch_bounds__(512, 4)
void head_fused(const unsigned short* __restrict__ hid_b,
                const unsigned short* __restrict__ w1_b, const float* __restrict__ b1,
                const unsigned short* __restrict__ w2_b, const float* __restrict__ b2,
                const int* __restrict__ posmap, float* __restrict__ out) {
    __shared__ unsigned short mid_s[HM * NMID];  // 64 KB

    int lane = threadIdx.x & 63;
    int wv = threadIdx.x >> 6;
    int mbase = blockIdx.x * HM;
    int lr = lane & 15;
    int kg = (lane >> 4) * 8;
    int rbase = (lane >> 4) * 4;
    int n0w = wv * 64;

    f32x4 acc[4][4];

    // ---- phase 1: mid tile
    #pragma unroll
    for (int mi = 0; mi < 4; ++mi)
        #pragma unroll
        for (int ni = 0; ni < 4; ++ni) acc[mi][ni] = (f32x4){0.f, 0.f, 0.f, 0.f};
    {
        const unsigned short* abase = hid_b + ((size_t)(mbase + lr)) * NH + kg;
        const unsigned short* bbase = w1_b + ((size_t)(n0w + lr)) * NH + kg;
        for (int k0 = 0; k0 < NH; k0 += 32) {
            bf16x8 af[4], bfr[4];
            #pragma unroll
            for (int mi = 0; mi < 4; ++mi) af[mi] = *(const bf16x8*)(abase + mi * 16 * NH + k0);
            #pragma unroll
            for (int ni = 0; ni < 4; ++ni) bfr[ni] = *(const bf16x8*)(bbase + ni * 16 * NH + k0);
            #pragma unroll
            for (int mi = 0; mi < 4; ++mi)
                #pragma unroll
                for (int ni = 0; ni < 4; ++ni)
                    acc[mi][ni] = __builtin_amdgcn_mfma_f32_16x16x32_bf16(af[mi], bfr[ni], acc[mi][ni], 0, 0, 0);
        }
    }
    #pragma unroll
    for (int mi = 0; mi < 4; ++mi)
        #pragma unroll
        for (int ni = 0; ni < 4; ++ni) {
            int col = n0w + ni * 16 + lr;
            float bv = b1[col];
            #pragma unroll
            for (int j = 0; j < 4; ++j) {
                int row = mi * 16 + rbase + j;
                float v = sigm(acc[mi][ni][j] + bv);
                int byteoff = ((row * NMID + col) * 2) ^ ((row & 7) << 4);
                *(unsigned short*)((char*)mid_s + byteoff) = f2bf(v);
            }
        }
    __syncthreads();

    // ---- phase 2: out tile
    #pragma unroll
    for (int mi = 0; mi < 4; ++mi)
        #pragma unroll
        for (int ni = 0; ni < 4; ++ni) acc[mi][ni] = (f32x4){0.f, 0.f, 0.f, 0.f};
    {
        const unsigned short* bbase = w2_b + ((size_t)(n0w + lr)) * NMID + kg;
        for (int k0 = 0; k0 < NMID; k0 += 32) {
            bf16x8 af[4], bfr[4];
            #pragma unroll
            for (int mi = 0; mi < 4; ++mi) {
                int row = mi * 16 + lr;
                int byteoff = ((row * NMID + k0 + kg) * 2) ^ ((row & 7) << 4);
                af[mi] = *(const bf16x8*)((char*)mid_s + byteoff);
            }
            #pragma unroll
            for (int ni = 0; ni < 4; ++ni) bfr[ni] = *(const bf16x8*)(bbase + ni * 16 * NMID + k0);
            #pragma unroll
            for (int mi = 0; mi < 4; ++mi)
                #pragma unroll
                for (int ni = 0; ni < 4; ++ni)
                    acc[mi][ni] = __builtin_amdgcn_mfma_f32_16x16x32_bf16(af[mi], bfr[ni], acc[mi][ni], 0, 0, 0);
        }
    }
    #pragma unroll
    for (int mi = 0; mi < 4; ++mi)
        #pragma unroll
        for (int ni = 0; ni < 4; ++ni) {
            int col = n0w + ni * 16 + lr;
            float bv = b2[col];
            #pragma unroll
            for (int j = 0; j < 4; ++j) {
                int row = mbase + mi * 16 + rbase + j;
                int b = row & 31;
                int node = row >> 5;
                int pos = posmap[node];
                out[((size_t)pos * NB + b) * NV + col] = acc[mi][ni][j] + bv;
            }
        }
}

extern "C" void kernel_launch(void* const* d_in, const int* in_sizes, int n_in,
                              void* d_out, int out_size, void* d_ws, size_t ws_size,
                              hipStream_t stream) {
    const float* root      = (const float*)d_in[0];
    const float* ann_table = (const float*)d_in[1];
    const float* w1        = (const float*)d_in[2];
    const float* b1        = (const float*)d_in[3];
    const float* w2        = (const float*)d_in[4];
    const float* b2        = (const float*)d_in[5];
    const float* w_ih      = (const float*)d_in[6];
    const float* w_hh      = (const float*)d_in[7];
    const float* b_ih      = (const float*)d_in[8];
    const float* b_hh      = (const float*)d_in[9];
    const int*   ann_ids   = (const int*)d_in[10];

    uint8_t* ws = (uint8_t*)d_ws;
    unsigned short* whh_b = (unsigned short*)ws; ws += (size_t)NG * NH * 2;
    unsigned short* w1_b  = (unsigned short*)ws; ws += (size_t)NMID * NH * 2;
    unsigned short* w2_b  = (unsigned short*)ws; ws += (size_t)NV * NMID * 2;
    float* gx_t           = (float*)ws;          ws += (size_t)NB * NG * 4;
    int* posmap           = (int*)ws;            ws += (size_t)NNODES * 4;
    unsigned short* hid_b = (unsigned short*)ws; ws += (size_t)NNODES * NB * NH * 2;

    cast_weights<<<512, 256, 0, stream>>>(w_hh, w1, w2, whh_b, w1_b, w2_b);
    gx_kernel<<<(NB * NG) / 4, 256, 0, stream>>>(ann_table, ann_ids, w_ih, b_ih, gx_t);
    init_root<<<(NB * NH + 255) / 256, 256, 0, stream>>>(root, hid_b);
    posmap_kernel<<<(NNODES + 255) / 256, 256, 0, stream>>>(posmap);

    int start = 0, cnt = 1;
    for (int l = 0; l < NDEPTH; ++l) {
        int child_start = start + cnt;
        if (cnt >= 512) {
            gru_level<6><<<dim3(cnt, 1), 512, 0, stream>>>(hid_b, hid_b, whh_b, b_hh, gx_t, start, child_start);
        } else if (cnt >= 128) {
            gru_level<2><<<dim3(cnt, 3), 512, 0, stream>>>(hid_b, hid_b, whh_b, b_hh, gx_t, start, child_start);
        } else {
            gru_level<1><<<dim3(cnt, 6), 512, 0, stream>>>(hid_b, hid_b, whh_b, b_hh, gx_t, start, child_start);
        }
        start = child_start; cnt *= 3;
    }
    head_fused<<<MROWS / HM, 512, 0, stream>>>(hid_b, w1_b, b1, w2_b, b2, posmap, (float*)d_out);
}

// Round 5
// 373.862 us; speedup vs baseline: 2.3025x; 1.3730x over previous
//
#include <hip/hip_runtime.h>
#include <hip/hip_bf16.h>
#include <stdint.h>
#include <stddef.h>

// Problem constants (GRUTridentDecoder: B=32,H=256,V=512,A=3,NANN=8,DEPTH=7)
#define NB 32
#define NH 256
#define NMID 512      // 2*H
#define NV 512
#define NA 3
#define NDEPTH 7
#define NNODES 3280   // (3^8-1)/2
#define NG 2304       // A*3H
#define MROWS (NNODES * NB)  // 104960
#define HM 64         // fused-head rows per block

typedef __attribute__((ext_vector_type(8))) short bf16x8;
typedef __attribute__((ext_vector_type(4))) float f32x4;

__device__ __forceinline__ unsigned short f2bf(float x) {
    union { float f; unsigned u; } v; v.f = x;
    unsigned r = v.u + 0x7fffu + ((v.u >> 16) & 1u);
    return (unsigned short)(r >> 16);
}
__device__ __forceinline__ float bf2f(unsigned short u) {
    union { unsigned u; float f; } v; v.u = ((unsigned)u) << 16;
    return v.f;
}
__device__ __forceinline__ float sigm(float x) { return 1.0f / (1.0f + __expf(-x)); }
__device__ __forceinline__ float tanh_(float x) {
    x = fminf(fmaxf(x, -15.0f), 15.0f);
    float e = __expf(2.0f * x);
    return (e - 1.0f) / (e + 1.0f);
}
__device__ __forceinline__ f32x4 splat4(float s) { f32x4 v = {s, s, s, s}; return v; }

// ---- prep: cast weights fp32 -> bf16
__global__ void cast_weights(const float* __restrict__ whh, const float* __restrict__ w1,
                             const float* __restrict__ w2,
                             unsigned short* __restrict__ whh_b,
                             unsigned short* __restrict__ w1_b,
                             unsigned short* __restrict__ w2_b) {
    const int n_whh = NG * NH;
    const int n_w1  = NMID * NH;
    const int n_w2  = NV * NMID;
    const int total = n_whh + n_w1 + n_w2;
    for (int i = blockIdx.x * blockDim.x + threadIdx.x; i < total;
         i += gridDim.x * blockDim.x) {
        if (i < n_whh) whh_b[i] = f2bf(whh[i]);
        else if (i < n_whh + n_w1) w1_b[i - n_whh] = f2bf(w1[i - n_whh]);
        else w2_b[i - n_whh - n_w1] = f2bf(w2[i - n_whh - n_w1]);
    }
}

// ---- prep: gx_t[col][b] = dot(ann_table[ann_ids[b]], w_ih[col]) + b_ih[col]  (TRANSPOSED)
__global__ void gx_kernel(const float* __restrict__ ann_table, const int* __restrict__ ann_ids,
                          const float* __restrict__ w_ih, const float* __restrict__ b_ih,
                          float* __restrict__ gx_t) {
    int gw = blockIdx.x * (blockDim.x >> 6) + (threadIdx.x >> 6);
    int lane = threadIdx.x & 63;
    if (gw >= NB * NG) return;
    int b = gw / NG;
    int col = gw - b * NG;
    const float* xr = ann_table + (size_t)ann_ids[b] * NH;
    const float* wr = w_ih + (size_t)col * NH;
    float4 xv = *(const float4*)(xr + lane * 4);
    float4 wv = *(const float4*)(wr + lane * 4);
    float s = xv.x * wv.x + xv.y * wv.y + xv.z * wv.z + xv.w * wv.w;
    #pragma unroll
    for (int off = 32; off; off >>= 1) s += __shfl_down(s, off);
    if (lane == 0) gx_t[(size_t)col * NB + b] = s + b_ih[col];
}

// ---- prep: root hidden into node 0 (bf16 only)
__global__ void init_root(const float* __restrict__ root, unsigned short* __restrict__ hid_b) {
    int i = blockIdx.x * blockDim.x + threadIdx.x;
    if (i < NB * NH) hid_b[i] = f2bf(root[i]);
}

// ---- prep: preorder position of each level-order node
__global__ void posmap_kernel(int* __restrict__ posmap) {
    int n = blockIdx.x * blockDim.x + threadIdx.x;
    if (n >= NNODES) return;
    int start = 0, cnt = 1, l = 0;
    while (n >= start + cnt) { start += cnt; cnt *= 3; l++; }
    int p = n - start;
    int pw = 1;
    for (int j = 0; j < l - 1; j++) pw *= 3;
    int pos = 0;
    for (int k = 1; k <= l; k++) {
        int d = (p / pw) % 3;
        int e = NDEPTH - k + 1;
        int p3 = 1; for (int j = 0; j < e; j++) p3 *= 3;
        pos += 1 + d * ((p3 - 1) / 2);
        pw /= 3;
    }
    posmap[n] = pos;
}

// ---- GRU level v4: NPB nodes per blockIdx.x (M = 32*NPB rows); 6 column-splits
// across blockIdx.y; wave wv owns 16 flat (a,h') cols, all 3 gates, all M rows.
// A staged in swizzled LDS; B double-buffered from L2; gx folded into acc-init.
template<int NPB>
__global__ __launch_bounds__(512, 4)
void gru_level(const unsigned short* __restrict__ hid_b_in,
               unsigned short* __restrict__ hid_b_out,
               const unsigned short* __restrict__ whh_b,
               const float* __restrict__ b_hh, const float* __restrict__ gx_t,
               int start, int child_start, int cnt) {
    constexpr int M = 32 * NPB;
    __shared__ char a_s[M * 512];   // M rows x 256 bf16, swizzled (row&15)<<4

    int tid = threadIdx.x;
    int lane = tid & 63;
    int wv = tid >> 6;
    int lr = lane & 15;
    int kg = (lane >> 4) * 8;
    int rbase = (lane >> 4) * 4;
    int nrel0 = blockIdx.x * NPB;
    size_t prow0 = (size_t)(start + nrel0) * NB;

    // stage A-tile
    for (int c = tid; c < M * 32; c += 512) {
        int row = c >> 5;
        int coloff = (c & 31) * 8;
        bf16x8 v = *(const bf16x8*)(hid_b_in + (prow0 + row) * NH + coloff);
        *(bf16x8*)(a_s + ((row * 512 + coloff * 2) ^ ((row & 15) << 4))) = v;
    }
    __syncthreads();

    int Gb = (blockIdx.y * 8 + wv) * 16;   // flat col = a*256 + h'
    int a = Gb >> 8;
    int colh = (Gb & 255) + lr;
    int gcol = a * 768 + colh;
    const unsigned short* bptr = whh_b + (size_t)(a * 512 + Gb + lr) * NH + kg;

    float bhr = b_hh[gcol], bhz = b_hh[gcol + 256], bhn = b_hh[gcol + 512];

    f32x4 acc[3][2 * NPB];
    #pragma unroll
    for (int g = 0; g < 2; ++g) {
        f32x4 gr = *(const f32x4*)(gx_t + (size_t)gcol * NB + g * 16 + rbase);
        f32x4 gz = *(const f32x4*)(gx_t + (size_t)(gcol + 256) * NB + g * 16 + rbase);
        #pragma unroll
        for (int mi = g; mi < 2 * NPB; mi += 2) {
            acc[0][mi] = gr + splat4(bhr);
            acc[1][mi] = gz + splat4(bhz);
            acc[2][mi] = splat4(bhn);
        }
    }

    bf16x8 bcur[3];
    #pragma unroll
    for (int t = 0; t < 3; ++t) bcur[t] = *(const bf16x8*)(bptr + t * 256 * NH);
    #pragma unroll
    for (int k0 = 0; k0 < NH; k0 += 32) {
        bf16x8 bnxt[3];
        if (k0 + 32 < NH) {
            #pragma unroll
            for (int t = 0; t < 3; ++t) bnxt[t] = *(const bf16x8*)(bptr + t * 256 * NH + k0 + 32);
        }
        bf16x8 af[2 * NPB];
        #pragma unroll
        for (int mi = 0; mi < 2 * NPB; ++mi) {
            int row = mi * 16 + lr;
            af[mi] = *(const bf16x8*)(a_s + ((row * 512 + (k0 + kg) * 2) ^ ((row & 15) << 4)));
        }
        #pragma unroll
        for (int t = 0; t < 3; ++t)
            #pragma unroll
            for (int mi = 0; mi < 2 * NPB; ++mi)
                acc[t][mi] = __builtin_amdgcn_mfma_f32_16x16x32_bf16(af[mi], bcur[t], acc[t][mi], 0, 0, 0);
        if (k0 + 32 < NH) {
            #pragma unroll
            for (int t = 0; t < 3; ++t) bcur[t] = bnxt[t];
        }
    }

    // epilogue: gates + bf16 child writes; parent h from LDS; xn loaded here
    f32x4 gxn[2];
    #pragma unroll
    for (int g = 0; g < 2; ++g)
        gxn[g] = *(const f32x4*)(gx_t + (size_t)(gcol + 512) * NB + g * 16 + rbase);
    #pragma unroll
    for (int mi = 0; mi < 2 * NPB; ++mi) {
        #pragma unroll
        for (int j = 0; j < 4; ++j) {
            int row = mi * 16 + rbase + j;
            int ns = row >> 5;
            int b = row & 31;
            if (nrel0 + ns < cnt) {
                float r = sigm(acc[0][mi][j]);
                float z = sigm(acc[1][mi][j]);
                float nn = tanh_(gxn[mi & 1][j] + r * acc[2][mi][j]);
                unsigned short hpu = *(const unsigned short*)(a_s + ((row * 512 + colh * 2) ^ ((row & 15) << 4)));
                float hnew = (1.0f - z) * nn + z * bf2f(hpu);
                size_t crow = ((size_t)(child_start + (nrel0 + ns) * 3 + a)) * NB + b;
                hid_b_out[crow * NH + colh] = f2bf(hnew);
            }
        }
    }
}

// ---- fused head v2: A-tile staged in LDS (aliased into mid buffer), B-frags
// double-buffered from L2. 8 waves, wave owns 64 cols x 64 rows.
__global__ __launch_bounds__(512, 4)
void head_fused(const unsigned short* __restrict__ hid_b,
                const unsigned short* __restrict__ w1_b, const float* __restrict__ b1,
                const unsigned short* __restrict__ w2_b, const float* __restrict__ b2,
                const int* __restrict__ posmap, float* __restrict__ out) {
    __shared__ char smem[HM * NMID * 2];  // 64 KB: phase1 A-tile (32KB) then mid

    int tid = threadIdx.x;
    int lane = tid & 63;
    int wv = tid >> 6;
    int mbase = blockIdx.x * HM;
    int lr = lane & 15;
    int kg = (lane >> 4) * 8;
    int rbase = (lane >> 4) * 4;
    int n0w = wv * 64;

    // stage A (64 x 256 bf16, 512B rows) swizzled
    for (int c = tid; c < HM * 32; c += 512) {
        int row = c >> 5;
        int coloff = (c & 31) * 8;
        bf16x8 v = *(const bf16x8*)(hid_b + ((size_t)(mbase + row)) * NH + coloff);
        *(bf16x8*)(smem + ((row * 512 + coloff * 2) ^ ((row & 15) << 4))) = v;
    }
    __syncthreads();

    f32x4 acc[4][4];
    #pragma unroll
    for (int mi = 0; mi < 4; ++mi)
        #pragma unroll
        for (int ni = 0; ni < 4; ++ni) acc[mi][ni] = (f32x4){0.f, 0.f, 0.f, 0.f};

    // ---- phase 1: mid = sigmoid(A @ w1^T + b1); A from LDS, B dbuf from L2
    {
        const unsigned short* bbase = w1_b + ((size_t)(n0w + lr)) * NH + kg;
        bf16x8 bcur[4];
        #pragma unroll
        for (int ni = 0; ni < 4; ++ni) bcur[ni] = *(const bf16x8*)(bbase + ni * 16 * NH);
        #pragma unroll
        for (int k0 = 0; k0 < NH; k0 += 32) {
            bf16x8 bnxt[4];
            if (k0 + 32 < NH) {
                #pragma unroll
                for (int ni = 0; ni < 4; ++ni) bnxt[ni] = *(const bf16x8*)(bbase + ni * 16 * NH + k0 + 32);
            }
            bf16x8 af[4];
            #pragma unroll
            for (int mi = 0; mi < 4; ++mi) {
                int row = mi * 16 + lr;
                af[mi] = *(const bf16x8*)(smem + ((row * 512 + (k0 + kg) * 2) ^ ((row & 15) << 4)));
            }
            #pragma unroll
            for (int mi = 0; mi < 4; ++mi)
                #pragma unroll
                for (int ni = 0; ni < 4; ++ni)
                    acc[mi][ni] = __builtin_amdgcn_mfma_f32_16x16x32_bf16(af[mi], bcur[ni], acc[mi][ni], 0, 0, 0);
            if (k0 + 32 < NH) {
                #pragma unroll
                for (int ni = 0; ni < 4; ++ni) bcur[ni] = bnxt[ni];
            }
        }
    }
    __syncthreads();   // all A reads done before mid overwrites the region

    // epilogue 1: sigmoid -> bf16 -> LDS (1024B rows, swizzle (row&15)<<4)
    #pragma unroll
    for (int mi = 0; mi < 4; ++mi)
        #pragma unroll
        for (int ni = 0; ni < 4; ++ni) {
            int col = n0w + ni * 16 + lr;
            float bv = b1[col];
            #pragma unroll
            for (int j = 0; j < 4; ++j) {
                int row = mi * 16 + rbase + j;
                float v = sigm(acc[mi][ni][j] + bv);
                *(unsigned short*)(smem + ((row * 1024 + col * 2) ^ ((row & 15) << 4))) = f2bf(v);
            }
        }
    __syncthreads();

    // ---- phase 2: out = mid @ w2^T + b2
    #pragma unroll
    for (int mi = 0; mi < 4; ++mi)
        #pragma unroll
        for (int ni = 0; ni < 4; ++ni) acc[mi][ni] = (f32x4){0.f, 0.f, 0.f, 0.f};
    {
        const unsigned short* bbase = w2_b + ((size_t)(n0w + lr)) * NMID + kg;
        bf16x8 bcur[4];
        #pragma unroll
        for (int ni = 0; ni < 4; ++ni) bcur[ni] = *(const bf16x8*)(bbase + ni * 16 * NMID);
        #pragma unroll
        for (int k0 = 0; k0 < NMID; k0 += 32) {
            bf16x8 bnxt[4];
            if (k0 + 32 < NMID) {
                #pragma unroll
                for (int ni = 0; ni < 4; ++ni) bnxt[ni] = *(const bf16x8*)(bbase + ni * 16 * NMID + k0 + 32);
            }
            bf16x8 af[4];
            #pragma unroll
            for (int mi = 0; mi < 4; ++mi) {
                int row = mi * 16 + lr;
                af[mi] = *(const bf16x8*)(smem + ((row * 1024 + (k0 + kg) * 2) ^ ((row & 15) << 4)));
            }
            #pragma unroll
            for (int mi = 0; mi < 4; ++mi)
                #pragma unroll
                for (int ni = 0; ni < 4; ++ni)
                    acc[mi][ni] = __builtin_amdgcn_mfma_f32_16x16x32_bf16(af[mi], bcur[ni], acc[mi][ni], 0, 0, 0);
            if (k0 + 32 < NMID) {
                #pragma unroll
                for (int ni = 0; ni < 4; ++ni) bcur[ni] = bnxt[ni];
            }
        }
    }
    // epilogue 2: bias + permuted store
    #pragma unroll
    for (int mi = 0; mi < 4; ++mi)
        #pragma unroll
        for (int ni = 0; ni < 4; ++ni) {
            int col = n0w + ni * 16 + lr;
            float bv = b2[col];
            #pragma unroll
            for (int j = 0; j < 4; ++j) {
                int row = mbase + mi * 16 + rbase + j;
                int b = row & 31;
                int node = row >> 5;
                int pos = posmap[node];
                out[((size_t)pos * NB + b) * NV + col] = acc[mi][ni][j] + bv;
            }
        }
}

extern "C" void kernel_launch(void* const* d_in, const int* in_sizes, int n_in,
                              void* d_out, int out_size, void* d_ws, size_t ws_size,
                              hipStream_t stream) {
    const float* root      = (const float*)d_in[0];
    const float* ann_table = (const float*)d_in[1];
    const float* w1        = (const float*)d_in[2];
    const float* b1        = (const float*)d_in[3];
    const float* w2        = (const float*)d_in[4];
    const float* b2        = (const float*)d_in[5];
    const float* w_ih      = (const float*)d_in[6];
    const float* w_hh      = (const float*)d_in[7];
    const float* b_ih      = (const float*)d_in[8];
    const float* b_hh      = (const float*)d_in[9];
    const int*   ann_ids   = (const int*)d_in[10];

    uint8_t* ws = (uint8_t*)d_ws;
    unsigned short* whh_b = (unsigned short*)ws; ws += (size_t)NG * NH * 2;
    unsigned short* w1_b  = (unsigned short*)ws; ws += (size_t)NMID * NH * 2;
    unsigned short* w2_b  = (unsigned short*)ws; ws += (size_t)NV * NMID * 2;
    float* gx_t           = (float*)ws;          ws += (size_t)NB * NG * 4;
    int* posmap           = (int*)ws;            ws += (size_t)NNODES * 4;
    unsigned short* hid_b = (unsigned short*)ws; ws += (size_t)NNODES * NB * NH * 2;

    cast_weights<<<512, 256, 0, stream>>>(w_hh, w1, w2, whh_b, w1_b, w2_b);
    gx_kernel<<<(NB * NG) / 4, 256, 0, stream>>>(ann_table, ann_ids, w_ih, b_ih, gx_t);
    init_root<<<(NB * NH + 255) / 256, 256, 0, stream>>>(root, hid_b);
    posmap_kernel<<<(NNODES + 255) / 256, 256, 0, stream>>>(posmap);

    int start = 0, cnt = 1;
    for (int l = 0; l < NDEPTH; ++l) {
        int child_start = start + cnt;
        if (cnt >= 128) {
            gru_level<2><<<dim3((cnt + 1) / 2, 6), 512, 0, stream>>>(
                hid_b, hid_b, whh_b, b_hh, gx_t, start, child_start, cnt);
        } else {
            gru_level<1><<<dim3(cnt, 6), 512, 0, stream>>>(
                hid_b, hid_b, whh_b, b_hh, gx_t, start, child_start, cnt);
        }
        start = child_start; cnt *= 3;
    }
    head_fused<<<MROWS / HM, 512, 0, stream>>>(hid_b, w1_b, b1, w2_b, b2, posmap, (float*)d_out);
}